// Round 2
// baseline (5883.338 us; speedup 1.0000x reference)
//
#include <hip/hip_runtime.h>
#include <hip/hip_bf16.h>
#include <cstdint>
#include <cstddef>

// SimpleModuleNet: MoE CNN forward.
// B=128, C=128, E=16, H=W=64, PROJ=512, FC=1024, NANS=2
//
// ws layout (floats):
//   bufA: 16,777,216  (stem1 out (128,128,32,32); later proj out / f)
//   bufH:  4,194,304  (h (128,128,16,16), updated in place by expert blocks)
//   bufT:  4,194,304  (t1 inside expert block; later fc1 partials + fc1 out)
// total ~100.7 MB

// ---------------------------------------------------------------------------
// stem1: conv3x3 (3->128, 64x64, pad1) + relu + maxpool2 -> (128,128,32,32)
// thread = one pooled output pixel; blockIdx.y = oc (weights wave-uniform)
__global__ __launch_bounds__(256) void stem1_k(
    const float* __restrict__ img, const float* __restrict__ w1,
    const float* __restrict__ b1, float* __restrict__ out)
{
  const int oc  = blockIdx.y;
  const int idx = blockIdx.x * 256 + threadIdx.x;   // over B*32*32 = 131072
  const int b   = idx >> 10;
  const int pos = idx & 1023;
  const int py  = pos >> 5, px = pos & 31;

  float ws[27];
#pragma unroll
  for (int i = 0; i < 27; ++i) ws[i] = w1[oc * 27 + i];
  const float bias = b1[oc];

  float patch[3][4][4];
#pragma unroll
  for (int ic = 0; ic < 3; ++ic)
#pragma unroll
    for (int r = 0; r < 4; ++r)
#pragma unroll
      for (int c = 0; c < 4; ++c) {
        const int iy = 2 * py - 1 + r, ix = 2 * px - 1 + c;
        float v = 0.f;
        if (iy >= 0 && iy < 64 && ix >= 0 && ix < 64)
          v = img[(((size_t)b * 3 + ic) * 64 + iy) * 64 + ix];
        patch[ic][r][c] = v;
      }

  float mx = -1e30f;
#pragma unroll
  for (int i = 0; i < 2; ++i)
#pragma unroll
    for (int j = 0; j < 2; ++j) {
      float a = bias;
#pragma unroll
      for (int ic = 0; ic < 3; ++ic)
#pragma unroll
        for (int dy = 0; dy < 3; ++dy)
#pragma unroll
          for (int dx = 0; dx < 3; ++dx)
            a = fmaf(patch[ic][i + dy][j + dx], ws[ic * 9 + dy * 3 + dx], a);
      mx = fmaxf(mx, a);
    }
  out[(((size_t)b * 128 + oc) * 32 + py) * 32 + px] = fmaxf(mx, 0.f);
}

// ---------------------------------------------------------------------------
// Generic C128->C128 conv3x3 pad1, tiled 16x16 spatial, 16 oc per block.
// MODE 0: out = relu(conv)                       (expert conv1, H=16)
// MODE 1: out = relu(res + conv)                 (expert conv2, H=16, in-place ok)
// MODE 2: out = maxpool2(relu(conv))             (stem2, H=32 -> out 16x16)
// grid.x = B * (tilesX*tilesX), grid.y = 8 (oc tiles). 256 threads = tile pixels.
template<int MODE>
__global__ __launch_bounds__(256) void conv3x3_k(
    const float* __restrict__ in, const float* __restrict__ wbase,
    const float* __restrict__ bbase, const int* __restrict__ question, int col,
    const float* __restrict__ res, float* __restrict__ out, int H, int tilesX)
{
  const int nt   = tilesX * tilesX;
  const int b    = blockIdx.x / nt;
  const int tile = blockIdx.x - b * nt;
  const int ty0  = (tile / tilesX) * 16, tx0 = (tile % tilesX) * 16;
  const int ocb  = blockIdx.y * 16;

  int widx = 0;
  if constexpr (MODE != 2) widx = question[b * 8 + col];   // expert id, wave-uniform
  const float* Wb = wbase + (size_t)widx * (128 * 128 * 9);
  const float* Bb = bbase + (size_t)widx * 128;

  __shared__ float sIn[16][18][18];   // 20.7 KB: 16-ch slab with halo

  const int tid = threadIdx.x;
  const int py = tid >> 4, px = tid & 15;

  float acc[16];
#pragma unroll
  for (int oc = 0; oc < 16; ++oc) acc[oc] = Bb[ocb + oc];

  for (int icc = 0; icc < 8; ++icc) {
    // stage 16 input channels (with zero-padded halo) into LDS
    for (int s = tid; s < 16 * 18 * 18; s += 256) {
      const int ch = s / 324;
      const int rr = (s - ch * 324) / 18;
      const int cc = s - ch * 324 - rr * 18;
      const int gy = ty0 + rr - 1, gx = tx0 + cc - 1;
      float v = 0.f;
      if (gy >= 0 && gy < H && gx >= 0 && gx < H)
        v = in[(((size_t)b * 128 + icc * 16 + ch) * H + gy) * H + gx];
      sIn[ch][rr][cc] = v;
    }
    __syncthreads();

    for (int ic = 0; ic < 16; ++ic) {
      float iv[9];
#pragma unroll
      for (int dy = 0; dy < 3; ++dy)
#pragma unroll
        for (int dx = 0; dx < 3; ++dx)
          iv[dy * 3 + dx] = sIn[ic][py + dy][px + dx];
      const float* wp = Wb + (size_t)ocb * 1152 + (size_t)(icc * 16 + ic) * 9;
#pragma unroll
      for (int oc = 0; oc < 16; ++oc)
#pragma unroll
        for (int t = 0; t < 9; ++t)
          acc[oc] = fmaf(iv[t], wp[(size_t)oc * 1152 + t], acc[oc]);
    }
    __syncthreads();
  }

  if constexpr (MODE == 0) {
#pragma unroll
    for (int oc = 0; oc < 16; ++oc)
      out[(((size_t)b * 128 + ocb + oc) * 16 + py) * 16 + px] = fmaxf(acc[oc], 0.f);
  } else if constexpr (MODE == 1) {
#pragma unroll
    for (int oc = 0; oc < 16; ++oc) {
      const size_t o = (((size_t)b * 128 + ocb + oc) * 16 + py) * 16 + px;
      out[o] = fmaxf(res[o] + acc[oc], 0.f);
    }
  } else {
    // fused 2x2 maxpool via in-wave shuffles (tid = py*16+px; partners tid^1, tid^16)
#pragma unroll
    for (int oc = 0; oc < 16; ++oc) {
      float m = acc[oc];
      m = fmaxf(m, __shfl_xor(m, 1));
      m = fmaxf(m, __shfl_xor(m, 16));
      if (!(px & 1) && !(py & 1)) {
        const int gy = (ty0 + py) >> 1, gx = (tx0 + px) >> 1;
        out[(((size_t)b * 128 + ocb + oc) * 16 + gy) * 16 + gx] = fmaxf(m, 0.f);
      }
    }
  }
}

// ---------------------------------------------------------------------------
// proj: 1x1 conv (128->512) + relu + maxpool2 : (128,128,16,16) -> (128,512,8,8)
// block = (b, 32-oc tile); 256 threads = pixels; h[b] staged in LDS by 32-ch chunks
__global__ __launch_bounds__(256) void proj_k(
    const float* __restrict__ h, const float* __restrict__ pw,
    const float* __restrict__ pb, float* __restrict__ out)
{
  const int b = blockIdx.x >> 4, ot = blockIdx.x & 15;
  const int ocb = ot * 32;
  __shared__ float sH[32][256];   // 32 KB

  const int pix = threadIdx.x;
  float acc[32];
#pragma unroll
  for (int oc = 0; oc < 32; ++oc) acc[oc] = pb[ocb + oc];

  for (int icc = 0; icc < 4; ++icc) {
#pragma unroll
    for (int k = 0; k < 32; ++k)
      sH[k][pix] = h[((size_t)b * 128 + icc * 32 + k) * 256 + pix];
    __syncthreads();
#pragma unroll 2
    for (int ic = 0; ic < 32; ++ic) {
      const float hv = sH[ic][pix];
      const float* wp = pw + (size_t)ocb * 128 + icc * 32 + ic;
#pragma unroll
      for (int oc = 0; oc < 32; ++oc)
        acc[oc] = fmaf(hv, wp[(size_t)oc * 128], acc[oc]);
    }
    __syncthreads();
  }

  const int py = pix >> 4, px = pix & 15;
#pragma unroll
  for (int oc = 0; oc < 32; ++oc) {
    float m = acc[oc];
    m = fmaxf(m, __shfl_xor(m, 1));
    m = fmaxf(m, __shfl_xor(m, 16));
    if (!(px & 1) && !(py & 1))
      out[(((size_t)b * 512 + ocb + oc) * 8 + (py >> 1)) * 8 + (px >> 1)] = fmaxf(m, 0.f);
  }
}

// ---------------------------------------------------------------------------
// fc1: (128, 32768) @ (1024, 32768)^T, K split by 8 -> partials
// block = (16 j, k-slice); thread = (m, 8 j's); f chunk staged in LDS (pad 65)
__global__ __launch_bounds__(256) void fc1_k(
    const float* __restrict__ f, const float* __restrict__ w, float* __restrict__ part)
{
  const int jb = blockIdx.x * 16;
  const int ks = blockIdx.y;
  const int k0base = ks * 4096;
  const int tid = threadIdx.x;
  const int m = tid & 127;
  const int jg = __builtin_amdgcn_readfirstlane(tid >> 7);   // 0/1, wave-uniform

  __shared__ float sF[128][65];   // pad -> (m + kk) % 32 banks, conflict-free

  float acc[8] = {0, 0, 0, 0, 0, 0, 0, 0};
  for (int kc = 0; kc < 4096; kc += 64) {
    const int k0 = k0base + kc;
    __syncthreads();
    for (int s = tid; s < 8192; s += 256) {
      const int mm = s >> 6, kk = s & 63;
      sF[mm][kk] = f[(size_t)mm * 32768 + k0 + kk];
    }
    __syncthreads();
#pragma unroll 4
    for (int kk = 0; kk < 64; ++kk) {
      const float fv = sF[m][kk];
      const float* wp = w + (size_t)(jb + jg * 8) * 32768 + k0 + kk;
#pragma unroll
      for (int jo = 0; jo < 8; ++jo)
        acc[jo] = fmaf(fv, wp[(size_t)jo * 32768], acc[jo]);
    }
  }
#pragma unroll
  for (int jo = 0; jo < 8; ++jo)
    part[((size_t)ks * 128 + m) * 1024 + jb + jg * 8 + jo] = acc[jo];
}

__global__ __launch_bounds__(256) void fc1_red_k(
    const float* __restrict__ part, const float* __restrict__ bias, float* __restrict__ fo)
{
  const int i = blockIdx.x * 256 + threadIdx.x;   // 131072
  const int m = i >> 10, j = i & 1023;
  float s = bias[j];
#pragma unroll
  for (int ks = 0; ks < 8; ++ks) s += part[((size_t)ks * 128 + m) * 1024 + j];
  fo[i] = fmaxf(s, 0.f);
}

// ---------------------------------------------------------------------------
// fc2: (128,1024) @ (2,1024)^T + bias -> d_out (128,2)
__global__ __launch_bounds__(256) void fc2_k(
    const float* __restrict__ fo, const float* __restrict__ w2,
    const float* __restrict__ b2, float* __restrict__ out)
{
  const int m = blockIdx.x;
  const int tid = threadIdx.x;
  float a0 = 0.f, a1 = 0.f;
  for (int k = tid; k < 1024; k += 256) {
    const float fv = fo[(size_t)m * 1024 + k];
    a0 = fmaf(fv, w2[k], a0);
    a1 = fmaf(fv, w2[1024 + k], a1);
  }
#pragma unroll
  for (int o = 32; o > 0; o >>= 1) {
    a0 += __shfl_down(a0, o);
    a1 += __shfl_down(a1, o);
  }
  __shared__ float r0[4], r1[4];
  const int wid = tid >> 6;
  if ((tid & 63) == 0) { r0[wid] = a0; r1[wid] = a1; }
  __syncthreads();
  if (tid == 0) {
    out[(size_t)m * 2 + 0] = r0[0] + r0[1] + r0[2] + r0[3] + b2[0];
    out[(size_t)m * 2 + 1] = r1[0] + r1[1] + r1[2] + r1[3] + b2[1];
  }
}

// ---------------------------------------------------------------------------
extern "C" void kernel_launch(void* const* d_in, const int* in_sizes, int n_in,
                              void* d_out, int out_size, void* d_ws, size_t ws_size,
                              hipStream_t stream)
{
  const float* image   = (const float*)d_in[0];
  const int*   question= (const int*)  d_in[1];
  const float* stem_w1 = (const float*)d_in[2];
  const float* stem_b1 = (const float*)d_in[3];
  const float* stem_w2 = (const float*)d_in[4];
  const float* stem_b2 = (const float*)d_in[5];
  const float* exp_w1  = (const float*)d_in[6];
  const float* exp_b1  = (const float*)d_in[7];
  const float* exp_w2  = (const float*)d_in[8];
  const float* exp_b2  = (const float*)d_in[9];
  const float* proj_w  = (const float*)d_in[10];
  const float* proj_b  = (const float*)d_in[11];
  const float* fc1_w   = (const float*)d_in[12];
  const float* fc1_b   = (const float*)d_in[13];
  const float* fc2_w   = (const float*)d_in[14];
  const float* fc2_b   = (const float*)d_in[15];
  float* out = (float*)d_out;

  float* bufA = (float*)d_ws;            // 16,777,216 floats
  float* bufH = bufA + 16777216;         //  4,194,304 floats
  float* bufT = bufH + 4194304;          //  4,194,304 floats
  float* part = bufT;                    // fc1 partials (8*128*1024 = 1,048,576)
  float* f1o  = bufT + 2097152;          // fc1 out (131,072)

  // stem
  stem1_k<<<dim3(512, 128), 256, 0, stream>>>(image, stem_w1, stem_b1, bufA);
  conv3x3_k<2><<<dim3(128 * 4, 8), 256, 0, stream>>>(bufA, stem_w2, stem_b2, nullptr, 0,
                                                     nullptr, bufH, 32, 2);
  // expert residual blocks, routing cols (3,4,6,7,5)
  const int cols[5] = {3, 4, 6, 7, 5};
  for (int i = 0; i < 5; ++i) {
    conv3x3_k<0><<<dim3(128, 8), 256, 0, stream>>>(bufH, exp_w1, exp_b1, question, cols[i],
                                                   nullptr, bufT, 16, 1);
    conv3x3_k<1><<<dim3(128, 8), 256, 0, stream>>>(bufT, exp_w2, exp_b2, question, cols[i],
                                                   bufH, bufH, 16, 1);
  }
  // head
  proj_k<<<2048, 256, 0, stream>>>(bufH, proj_w, proj_b, bufA);
  fc1_k<<<dim3(64, 8), 256, 0, stream>>>(bufA, fc1_w, part);
  fc1_red_k<<<512, 256, 0, stream>>>(part, fc1_b, f1o);
  fc2_k<<<128, 256, 0, stream>>>(f1o, fc2_w, fc2_b, out);
}

// Round 3
// 1102.228 us; speedup vs baseline: 5.3377x; 5.3377x over previous
//
#include <hip/hip_runtime.h>
#include <hip/hip_bf16.h>
#include <cstdint>
#include <cstddef>

// SimpleModuleNet MoE CNN forward — bf16 MFMA implicit-GEMM version.
// B=128, C=128, E=16, H=W=64, PROJ=512, FC=1024, NANS=2
//
// Conv formulation: out[oc][px] = sum_k w[oc][k] * in_patch[k][px], k=(ic,dy,dx),
// decomposed per (dy,dx) so a k-run of 8 = 8 consecutive ic (contiguous in both
// the transformed weights [oc][dydx][ic] and channels-last activations [y][x][ic]).
// MFMA v_mfma_f32_32x32x16_bf16: A,B fragments use the SAME slot convention
// k = (lane>>5)*8 + j  => any hardware k-permutation cancels (consistency).
// C/D layout (HW-verified): col = lane&31 (=px), row = (r&3)+8*(r>>2)+4*(lane>>5) (=oc).

typedef __bf16 bf16_t;
typedef __attribute__((ext_vector_type(4))) bf16_t bf16x4;
typedef __attribute__((ext_vector_type(8))) bf16_t bf16x8;
typedef __attribute__((ext_vector_type(16))) float f32x16;
typedef __attribute__((ext_vector_type(4))) float f32x4;

// ---------------------------------------------------------------------------
// Weight transform: [R rows][128 ic][3][3] fp32 -> [R][9 dydx][128 ic] bf16
__global__ __launch_bounds__(256) void wconv_k(
    const float* __restrict__ in, bf16_t* __restrict__ out)
{
  const int r = blockIdx.x;
  const float* ip = in + (size_t)r * 1152;
  bf16_t* op = out + (size_t)r * 1152;
  for (int t = threadIdx.x; t < 1152; t += 256) {
    const int dd = t >> 7, ic = t & 127;   // t = dd*128+ic, dd in 0..8
    op[t] = (bf16_t)ip[ic * 9 + dd];
  }
}

// proj weights [512][128] fp32 -> bf16 (layout already [oc][ic])
__global__ __launch_bounds__(256) void pconv_k(
    const float* __restrict__ in, bf16_t* __restrict__ out)
{
  const int i = blockIdx.x * 256 + threadIdx.x;   // 65536
  out[i] = (bf16_t)in[i];
}

// ---------------------------------------------------------------------------
// stem1: conv3x3 (3->128, 64x64, pad1) + relu + maxpool2 -> bf16 NCHW (128,128,32,32)
__global__ __launch_bounds__(256) void stem1_k(
    const float* __restrict__ img, const float* __restrict__ w1,
    const float* __restrict__ b1, bf16_t* __restrict__ out)
{
  const int oc  = blockIdx.y;
  const int idx = blockIdx.x * 256 + threadIdx.x;   // B*32*32 = 131072
  const int b   = idx >> 10;
  const int pos = idx & 1023;
  const int py  = pos >> 5, px = pos & 31;

  float ws[27];
#pragma unroll
  for (int i = 0; i < 27; ++i) ws[i] = w1[oc * 27 + i];
  const float bias = b1[oc];

  float patch[3][4][4];
#pragma unroll
  for (int ic = 0; ic < 3; ++ic)
#pragma unroll
    for (int r = 0; r < 4; ++r)
#pragma unroll
      for (int c = 0; c < 4; ++c) {
        const int iy = 2 * py - 1 + r, ix = 2 * px - 1 + c;
        float v = 0.f;
        if (iy >= 0 && iy < 64 && ix >= 0 && ix < 64)
          v = img[(((size_t)b * 3 + ic) * 64 + iy) * 64 + ix];
        patch[ic][r][c] = v;
      }

  float mx = -1e30f;
#pragma unroll
  for (int i = 0; i < 2; ++i)
#pragma unroll
    for (int j = 0; j < 2; ++j) {
      float a = bias;
#pragma unroll
      for (int ic = 0; ic < 3; ++ic)
#pragma unroll
        for (int dy = 0; dy < 3; ++dy)
#pragma unroll
          for (int dx = 0; dx < 3; ++dx)
            a = fmaf(patch[ic][i + dy][j + dx], ws[ic * 9 + dy * 3 + dx], a);
      mx = fmaxf(mx, a);
    }
  out[(((size_t)b * 128 + oc) * 32 + py) * 32 + px] = (bf16_t)fmaxf(mx, 0.f);
}

// ---------------------------------------------------------------------------
// NCHW bf16 (128c x 1024px per b) -> NHWC bf16 (1024px x 128c per b)
__global__ __launch_bounds__(256) void t1_k(
    const bf16_t* __restrict__ in, bf16_t* __restrict__ out)
{
  const int bid = blockIdx.x;           // 128*16
  const int b = bid >> 4, pt = bid & 15;
  __shared__ bf16_t sT[128][76];
  const int tid = threadIdx.x;
  const int cbase = tid >> 4, px4 = (tid & 15) * 4;
#pragma unroll
  for (int it = 0; it < 8; ++it) {
    const int c = it * 16 + cbase;
    bf16x4 v = *(const bf16x4*)(in + ((size_t)(b * 128 + c)) * 1024 + pt * 64 + px4);
    *(bf16x4*)(&sT[c][px4]) = v;
  }
  __syncthreads();
  const int p = tid >> 2, cg = tid & 3;
#pragma unroll
  for (int vv = 0; vv < 4; ++vv) {
    bf16x8 o;
#pragma unroll
    for (int j = 0; j < 8; ++j) o[j] = sT[cg * 32 + vv * 8 + j][p];
    *(bf16x8*)(out + ((size_t)(b * 1024 + pt * 64 + p)) * 128 + cg * 32 + vv * 8) = o;
  }
}

// ---------------------------------------------------------------------------
// stem2: conv3x3 128->128 on 32x32 NHWC bf16 + relu + maxpool2 -> 16x16 NHWC bf16
// grid = 128 b * 4 ph (8 conv rows each); 256 thr = 4 waves (2 oc-halves x 2 row-halves)
__global__ __launch_bounds__(256) void conv_stem2_k(
    const bf16_t* __restrict__ act, const bf16_t* __restrict__ wT,
    const float* __restrict__ bias, bf16_t* __restrict__ out)
{
  const int b = blockIdx.x >> 2, ph = blockIdx.x & 3;
  const int y0 = ph * 8;
  const int tid = threadIdx.x, lane = tid & 63, wv = tid >> 6;
  const int g = lane >> 5, cc = lane & 31;
  const int wq_oc = wv & 1, wq_px = wv >> 1;

  __shared__ bf16_t simg[10 * 34 * 64];   // 43.5 KB

  f32x16 acc[2][4];
#pragma unroll
  for (int i = 0; i < 2; ++i)
#pragma unroll
    for (int j = 0; j < 4; ++j)
#pragma unroll
      for (int r = 0; r < 16; ++r) acc[i][j][r] = 0.f;

  int sl[4];
#pragma unroll
  for (int nf = 0; nf < 4; ++nf) sl[nf] = (wq_px * 4 + nf) * 34 + cc;

  const int ocr0 = wq_oc * 64 + cc;
  const bf16_t* wrow0 = wT + (size_t)ocr0 * 1152;
  const bf16_t* wrow1 = wrow0 + 32 * 1152;

  for (int ich = 0; ich < 2; ++ich) {
    __syncthreads();
    for (int p = tid; p < 340; p += 256) {
      const int yy = p / 34, xx = p - yy * 34;
      const int gy = y0 + yy - 1, gx = xx - 1;
      const bool inb = (gy >= 0 && gy < 32 && gx >= 0 && gx < 32);
      const bf16_t* src = act + ((size_t)(b * 1024 + gy * 32 + gx)) * 128 + ich * 64;
#pragma unroll
      for (int j = 0; j < 8; ++j) {
        bf16x8 v = {};
        if (inb) v = *(const bf16x8*)(src + j * 8);
        const int waddr = (p * 128 + j * 16) ^ ((p & 7) << 4);
        *(bf16x8*)((char*)simg + waddr) = v;
      }
    }
    __syncthreads();

    for (int dydx = 0; dydx < 9; ++dydx) {
      const int dy = dydx / 3, dx = dydx - dy * 3;
      const int sb = dy * 34 + dx;
      const bf16_t* wp0 = wrow0 + dydx * 128 + ich * 64 + g * 8;
      const bf16_t* wp1 = wrow1 + dydx * 128 + ich * 64 + g * 8;
#pragma unroll
      for (int kh = 0; kh < 4; ++kh) {
        const bf16x8 a0 = *(const bf16x8*)(wp0 + kh * 16);
        const bf16x8 a1 = *(const bf16x8*)(wp1 + kh * 16);
#pragma unroll
        for (int nf = 0; nf < 4; ++nf) {
          const int s = sl[nf] + sb;
          const int raddr = (s * 128 + (kh * 2 + g) * 16) ^ ((s & 7) << 4);
          const bf16x8 bb = *(const bf16x8*)((const char*)simg + raddr);
          acc[0][nf] = __builtin_amdgcn_mfma_f32_32x32x16_bf16(a0, bb, acc[0][nf], 0, 0, 0);
          acc[1][nf] = __builtin_amdgcn_mfma_f32_32x32x16_bf16(a1, bb, acc[1][nf], 0, 0, 0);
        }
      }
    }
  }

  // epilogue: bias -> pool(2x2) -> relu -> NHWC bf16
#pragma unroll
  for (int mf = 0; mf < 2; ++mf) {
#pragma unroll
    for (int q = 0; q < 2; ++q) {
      const int py = (y0 + wq_px * 4 + 2 * q) >> 1;
      const int pxp = cc >> 1;
      bf16_t* op = out + ((size_t)(b * 256 + py * 16 + pxp)) * 128;
#pragma unroll
      for (int rq = 0; rq < 4; ++rq) {
        const int oc4 = wq_oc * 64 + mf * 32 + rq * 8 + g * 4;
        const f32x4 bi = *(const f32x4*)(bias + oc4);
        bf16x4 qv;
#pragma unroll
        for (int j = 0; j < 4; ++j) {
          const int r = rq * 4 + j;
          float v = fmaxf(acc[mf][2 * q][r], acc[mf][2 * q + 1][r]);
          v = fmaxf(v, __shfl_xor(v, 1));
          qv[j] = (bf16_t)fmaxf(v + bi[j], 0.f);
        }
        if ((cc & 1) == 0) *(bf16x4*)(op + oc4) = qv;
      }
    }
  }
}

// ---------------------------------------------------------------------------
// Expert conv3x3 128->128 on 16x16 NHWC bf16. RES=0: relu(conv+bias)
// RES=1: relu(res + conv + bias). grid = 128 b * 2 ph; 256 thr.
template<int RES>
__global__ __launch_bounds__(256) void conv_exp_k(
    const bf16_t* __restrict__ act, const bf16_t* __restrict__ wT,
    const float* __restrict__ bias, const int* __restrict__ question, int col,
    const bf16_t* __restrict__ res, bf16_t* __restrict__ out)
{
  const int b = blockIdx.x >> 1, ph = blockIdx.x & 1;
  const int y0 = ph * 8;
  const int e = question[b * 8 + col];
  const int tid = threadIdx.x, lane = tid & 63, wv = tid >> 6;
  const int g = lane >> 5, cc = lane & 31;
  const int wq_oc = wv & 1, wq_px = wv >> 1;

  __shared__ bf16_t simg[10 * 18 * 64];   // 22.5 KB

  f32x16 acc[2][2];
#pragma unroll
  for (int i = 0; i < 2; ++i)
#pragma unroll
    for (int j = 0; j < 2; ++j)
#pragma unroll
      for (int r = 0; r < 16; ++r) acc[i][j][r] = 0.f;

  const int px0 = wq_px * 64 + cc;
  int sl[2];
#pragma unroll
  for (int nf = 0; nf < 2; ++nf) {
    const int px = px0 + nf * 32;
    sl[nf] = (px >> 4) * 18 + (px & 15);
  }

  const bf16_t* wTe = wT + (size_t)e * (128 * 1152);
  const int ocr0 = wq_oc * 64 + cc;
  const bf16_t* wrow0 = wTe + (size_t)ocr0 * 1152;
  const bf16_t* wrow1 = wrow0 + 32 * 1152;

  for (int ich = 0; ich < 2; ++ich) {
    __syncthreads();
    for (int p = tid; p < 180; p += 256) {
      const int yy = p / 18, xx = p - yy * 18;
      const int gy = y0 + yy - 1, gx = xx - 1;
      const bool inb = (gy >= 0 && gy < 16 && gx >= 0 && gx < 16);
      const bf16_t* src = act + ((size_t)(b * 256 + gy * 16 + gx)) * 128 + ich * 64;
#pragma unroll
      for (int j = 0; j < 8; ++j) {
        bf16x8 v = {};
        if (inb) v = *(const bf16x8*)(src + j * 8);
        const int waddr = (p * 128 + j * 16) ^ ((p & 7) << 4);
        *(bf16x8*)((char*)simg + waddr) = v;
      }
    }
    __syncthreads();

    for (int dydx = 0; dydx < 9; ++dydx) {
      const int dy = dydx / 3, dx = dydx - dy * 3;
      const int sb = dy * 18 + dx;
      const bf16_t* wp0 = wrow0 + dydx * 128 + ich * 64 + g * 8;
      const bf16_t* wp1 = wrow1 + dydx * 128 + ich * 64 + g * 8;
#pragma unroll
      for (int kh = 0; kh < 4; ++kh) {
        const bf16x8 a0 = *(const bf16x8*)(wp0 + kh * 16);
        const bf16x8 a1 = *(const bf16x8*)(wp1 + kh * 16);
#pragma unroll
        for (int nf = 0; nf < 2; ++nf) {
          const int s = sl[nf] + sb;
          const int raddr = (s * 128 + (kh * 2 + g) * 16) ^ ((s & 7) << 4);
          const bf16x8 bb = *(const bf16x8*)((const char*)simg + raddr);
          acc[0][nf] = __builtin_amdgcn_mfma_f32_32x32x16_bf16(a0, bb, acc[0][nf], 0, 0, 0);
          acc[1][nf] = __builtin_amdgcn_mfma_f32_32x32x16_bf16(a1, bb, acc[1][nf], 0, 0, 0);
        }
      }
    }
  }

  const float* bb = bias + e * 128;
#pragma unroll
  for (int mf = 0; mf < 2; ++mf) {
#pragma unroll
    for (int nf = 0; nf < 2; ++nf) {
      const int px = px0 + nf * 32;
      const int yl = px >> 4, x = px & 15;
      const size_t pixbase = ((size_t)(b * 256 + (y0 + yl) * 16 + x)) * 128;
      bf16_t* op = out + pixbase;
#pragma unroll
      for (int rq = 0; rq < 4; ++rq) {
        const int oc4 = wq_oc * 64 + mf * 32 + rq * 8 + g * 4;
        const f32x4 bi = *(const f32x4*)(bb + oc4);
        bf16x4 qv;
        bf16x4 rv = {};
        if (RES) rv = *(const bf16x4*)(res + pixbase + oc4);
#pragma unroll
        for (int j = 0; j < 4; ++j) {
          float v = acc[mf][nf][rq * 4 + j] + bi[j];
          if (RES) v += (float)rv[j];
          qv[j] = (bf16_t)fmaxf(v, 0.f);
        }
        *(bf16x4*)(op + oc4) = qv;
      }
    }
  }
}

// ---------------------------------------------------------------------------
// proj 1x1 conv 128->512 + relu + maxpool2, NHWC bf16 in -> NCHW fp32 f (128,512,8,8)
// grid = 128 b * 4 ocg(128 oc each); 256 thr.
__global__ __launch_bounds__(256) void proj_mfma_k(
    const bf16_t* __restrict__ h, const bf16_t* __restrict__ pw,
    const float* __restrict__ pb, float* __restrict__ f)
{
  const int b = blockIdx.x >> 2, ocg = blockIdx.x & 3;
  const int tid = threadIdx.x, lane = tid & 63, wv = tid >> 6;
  const int g = lane >> 5, cc = lane & 31;
  const int wq_oc = wv & 1, wq_px = wv >> 1;

  __shared__ bf16_t simg[256 * 64];   // 32 KB

  f32x16 acc[2][4];
#pragma unroll
  for (int i = 0; i < 2; ++i)
#pragma unroll
    for (int j = 0; j < 4; ++j)
#pragma unroll
      for (int r = 0; r < 16; ++r) acc[i][j][r] = 0.f;

  const int px0 = wq_px * 128 + cc;
  const int ocr0 = ocg * 128 + wq_oc * 64 + cc;
  const bf16_t* wrow0 = pw + (size_t)ocr0 * 128;
  const bf16_t* wrow1 = wrow0 + 32 * 128;

  for (int ich = 0; ich < 2; ++ich) {
    __syncthreads();
    {
      const int p = tid;
      const bf16_t* src = h + ((size_t)(b * 256 + p)) * 128 + ich * 64;
#pragma unroll
      for (int j = 0; j < 8; ++j) {
        bf16x8 v = *(const bf16x8*)(src + j * 8);
        const int waddr = (p * 128 + j * 16) ^ ((p & 7) << 4);
        *(bf16x8*)((char*)simg + waddr) = v;
      }
    }
    __syncthreads();

#pragma unroll
    for (int kh = 0; kh < 4; ++kh) {
      const bf16x8 a0 = *(const bf16x8*)(wrow0 + ich * 64 + kh * 16 + g * 8);
      const bf16x8 a1 = *(const bf16x8*)(wrow1 + ich * 64 + kh * 16 + g * 8);
#pragma unroll
      for (int nf = 0; nf < 4; ++nf) {
        const int s = px0 + nf * 32;
        const int raddr = (s * 128 + (kh * 2 + g) * 16) ^ ((s & 7) << 4);
        const bf16x8 bb = *(const bf16x8*)((const char*)simg + raddr);
        acc[0][nf] = __builtin_amdgcn_mfma_f32_32x32x16_bf16(a0, bb, acc[0][nf], 0, 0, 0);
        acc[1][nf] = __builtin_amdgcn_mfma_f32_32x32x16_bf16(a1, bb, acc[1][nf], 0, 0, 0);
      }
    }
  }

  // bias -> pool -> relu -> f NCHW fp32
#pragma unroll
  for (int mf = 0; mf < 2; ++mf) {
#pragma unroll
    for (int nf = 0; nf < 4; ++nf) {
      const int px = px0 + nf * 32;
      const int x = px & 15;
      const int py = wq_px * 4 + nf;
      const int pxp = x >> 1;
#pragma unroll
      for (int r = 0; r < 16; ++r) {
        float v = acc[mf][nf][r];
        v = fmaxf(v, __shfl_xor(v, 1));
        v = fmaxf(v, __shfl_xor(v, 16));
        const int oc = ocg * 128 + wq_oc * 64 + mf * 32 + (r & 3) + 8 * (r >> 2) + 4 * g;
        v = fmaxf(v + pb[oc], 0.f);
        if ((cc & 17) == 0)
          f[((size_t)(b * 512 + oc)) * 64 + py * 8 + pxp] = v;
      }
    }
  }
}

// ---------------------------------------------------------------------------
// fc1: (128,32768) @ (1024,32768)^T fp32, K split by 8. Weights staged in LDS
// (coalesced) and broadcast — fixes the uniform-scalar-load bottleneck.
__global__ __launch_bounds__(256) void fc1_k(
    const float* __restrict__ f, const float* __restrict__ w, float* __restrict__ part)
{
  const int jb = blockIdx.x * 16;
  const int ks = blockIdx.y;
  const int k0base = ks * 4096;
  const int tid = threadIdx.x;
  const int m = tid & 127;
  const int jg = __builtin_amdgcn_readfirstlane(tid >> 7);

  __shared__ float sF[128][65];
  __shared__ float sW[16][65];

  float acc[8] = {0, 0, 0, 0, 0, 0, 0, 0};
  for (int kc = 0; kc < 4096; kc += 64) {
    const int k0 = k0base + kc;
    __syncthreads();
    for (int s = tid; s < 8192; s += 256) {
      const int mm = s >> 6, kk = s & 63;
      sF[mm][kk] = f[(size_t)mm * 32768 + k0 + kk];
    }
    for (int s = tid; s < 1024; s += 256) {
      const int n = s >> 6, kk = s & 63;
      sW[n][kk] = w[(size_t)(jb + n) * 32768 + k0 + kk];
    }
    __syncthreads();
#pragma unroll 4
    for (int kk = 0; kk < 64; ++kk) {
      const float fv = sF[m][kk];
#pragma unroll
      for (int jo = 0; jo < 8; ++jo)
        acc[jo] = fmaf(fv, sW[jg * 8 + jo][kk], acc[jo]);
    }
  }
#pragma unroll
  for (int jo = 0; jo < 8; ++jo)
    part[((size_t)ks * 128 + m) * 1024 + jb + jg * 8 + jo] = acc[jo];
}

__global__ __launch_bounds__(256) void fc1_red_k(
    const float* __restrict__ part, const float* __restrict__ bias, float* __restrict__ fo)
{
  const int i = blockIdx.x * 256 + threadIdx.x;   // 131072
  const int m = i >> 10, j = i & 1023;
  float s = bias[j];
#pragma unroll
  for (int ks = 0; ks < 8; ++ks) s += part[((size_t)ks * 128 + m) * 1024 + j];
  fo[i] = fmaxf(s, 0.f);
}

// ---------------------------------------------------------------------------
__global__ __launch_bounds__(256) void fc2_k(
    const float* __restrict__ fo, const float* __restrict__ w2,
    const float* __restrict__ b2, float* __restrict__ out)
{
  const int m = blockIdx.x;
  const int tid = threadIdx.x;
  float a0 = 0.f, a1 = 0.f;
  for (int k = tid; k < 1024; k += 256) {
    const float fv = fo[(size_t)m * 1024 + k];
    a0 = fmaf(fv, w2[k], a0);
    a1 = fmaf(fv, w2[1024 + k], a1);
  }
#pragma unroll
  for (int o = 32; o > 0; o >>= 1) {
    a0 += __shfl_down(a0, o);
    a1 += __shfl_down(a1, o);
  }
  __shared__ float r0[4], r1[4];
  const int wid = tid >> 6;
  if ((tid & 63) == 0) { r0[wid] = a0; r1[wid] = a1; }
  __syncthreads();
  if (tid == 0) {
    out[(size_t)m * 2 + 0] = r0[0] + r0[1] + r0[2] + r0[3] + b2[0];
    out[(size_t)m * 2 + 1] = r1[0] + r1[1] + r1[2] + r1[3] + b2[1];
  }
}

// ---------------------------------------------------------------------------
extern "C" void kernel_launch(void* const* d_in, const int* in_sizes, int n_in,
                              void* d_out, int out_size, void* d_ws, size_t ws_size,
                              hipStream_t stream)
{
  const float* image    = (const float*)d_in[0];
  const int*   question = (const int*)  d_in[1];
  const float* stem_w1  = (const float*)d_in[2];
  const float* stem_b1  = (const float*)d_in[3];
  const float* stem_w2  = (const float*)d_in[4];
  const float* stem_b2  = (const float*)d_in[5];
  const float* exp_w1   = (const float*)d_in[6];
  const float* exp_b1   = (const float*)d_in[7];
  const float* exp_w2   = (const float*)d_in[8];
  const float* exp_b2   = (const float*)d_in[9];
  const float* proj_w   = (const float*)d_in[10];
  const float* proj_b   = (const float*)d_in[11];
  const float* fc1_w    = (const float*)d_in[12];
  const float* fc1_b    = (const float*)d_in[13];
  const float* fc2_w    = (const float*)d_in[14];
  const float* fc2_b    = (const float*)d_in[15];
  float* out = (float*)d_out;

  char* base = (char*)d_ws;
  bf16_t* stem1o = (bf16_t*)base;                      // 33,554,432 B (bf16 NCHW 128x128x32x32)
  bf16_t* actA   = (bf16_t*)(base + 33554432);         // 33,554,432 B (NHWC 32x32)
  bf16_t* actH   = (bf16_t*)(base + 67108864);         //  8,388,608 B (NHWC 16x16)
  bf16_t* actT   = (bf16_t*)(base + 75497472);         //  8,388,608 B
  bf16_t* wT1    = (bf16_t*)(base + 83886080);         //  4,718,592 B
  bf16_t* wT2    = (bf16_t*)(base + 88604672);         //  4,718,592 B
  bf16_t* wTs2   = (bf16_t*)(base + 93323264);         //    294,912 B
  bf16_t* pwT    = (bf16_t*)(base + 93618176);         //    131,072 B
  // region0 reused after t1_k: f (fp32), fc1 partials, fc1 out
  float* fbuf = (float*)base;                          // 4,194,304 floats
  float* part = (float*)base + 4194304;                // 1,048,576 floats
  float* f1o  = (float*)base + 5242880;                //   131,072 floats

  // weight prep
  wconv_k<<<2048, 256, 0, stream>>>(exp_w1, wT1);
  wconv_k<<<2048, 256, 0, stream>>>(exp_w2, wT2);
  wconv_k<<<128, 256, 0, stream>>>(stem_w2, wTs2);
  pconv_k<<<256, 256, 0, stream>>>(proj_w, pwT);

  // stem
  stem1_k<<<dim3(512, 128), 256, 0, stream>>>(image, stem_w1, stem_b1, stem1o);
  t1_k<<<2048, 256, 0, stream>>>(stem1o, actA);
  conv_stem2_k<<<512, 256, 0, stream>>>(actA, wTs2, stem_b2, actH);

  // expert residual blocks, routing cols (3,4,6,7,5)
  const int cols[5] = {3, 4, 6, 7, 5};
  for (int i = 0; i < 5; ++i) {
    conv_exp_k<0><<<256, 256, 0, stream>>>(actH, wT1, exp_b1, question, cols[i],
                                           nullptr, actT);
    conv_exp_k<1><<<256, 256, 0, stream>>>(actT, wT2, exp_b2, question, cols[i],
                                           actH, actH);
  }

  // head
  proj_mfma_k<<<512, 256, 0, stream>>>(actH, pwT, proj_b, fbuf);
  fc1_k<<<dim3(64, 8), 256, 0, stream>>>(fbuf, fc1_w, part);
  fc1_red_k<<<512, 256, 0, stream>>>(part, fc1_b, f1o);
  fc2_k<<<128, 256, 0, stream>>>(f1o, fc2_w, fc2_b, out);
}

// Round 5
// 734.291 us; speedup vs baseline: 8.0123x; 1.5011x over previous
//
#include <hip/hip_runtime.h>
#include <hip/hip_bf16.h>
#include <cstdint>
#include <cstddef>

// SimpleModuleNet MoE CNN forward — bf16 MFMA implicit-GEMM version.
// B=128, C=128, E=16, H=W=64, PROJ=512, FC=1024, NANS=2
//
// Conv formulation: out[oc][px] = sum_k w[oc][k] * in_patch[k][px], k=(ic,dy,dx),
// decomposed per (dy,dx). MFMA v_mfma_f32_32x32x16_bf16; A,B fragments use the
// SAME slot convention k = (lane>>5)*8 + j  => any k-permutation cancels.
// C/D layout (HW-verified): col = lane&31, row = (r&3)+8*(r>>2)+4*(lane>>5).

typedef __bf16 bf16_t;
typedef __attribute__((ext_vector_type(4))) bf16_t bf16x4;
typedef __attribute__((ext_vector_type(8))) bf16_t bf16x8;
typedef __attribute__((ext_vector_type(16))) float f32x16;
typedef __attribute__((ext_vector_type(4))) float f32x4;

// ---------------------------------------------------------------------------
// Weight transform: [R rows][128 ic][3][3] fp32 -> [R][9 dydx][128 ic] bf16
__global__ __launch_bounds__(256) void wconv_k(
    const float* __restrict__ in, bf16_t* __restrict__ out)
{
  const int r = blockIdx.x;
  const float* ip = in + (size_t)r * 1152;
  bf16_t* op = out + (size_t)r * 1152;
  for (int t = threadIdx.x; t < 1152; t += 256) {
    const int dd = t >> 7, ic = t & 127;
    op[t] = (bf16_t)ip[ic * 9 + dd];
  }
}

// proj weights [512][128] fp32 -> bf16
__global__ __launch_bounds__(256) void pconv_k(
    const float* __restrict__ in, bf16_t* __restrict__ out)
{
  const int i = blockIdx.x * 256 + threadIdx.x;
  out[i] = (bf16_t)in[i];
}

// ---------------------------------------------------------------------------
// stem1: conv3x3 (3->128, 64x64, pad1) + relu + maxpool2 -> bf16 NCHW (128,128,32,32)
__global__ __launch_bounds__(256) void stem1_k(
    const float* __restrict__ img, const float* __restrict__ w1,
    const float* __restrict__ b1, bf16_t* __restrict__ out)
{
  const int oc  = blockIdx.y;
  const int idx = blockIdx.x * 256 + threadIdx.x;
  const int b   = idx >> 10;
  const int pos = idx & 1023;
  const int py  = pos >> 5, px = pos & 31;

  float ws[27];
#pragma unroll
  for (int i = 0; i < 27; ++i) ws[i] = w1[oc * 27 + i];
  const float bias = b1[oc];

  float patch[3][4][4];
#pragma unroll
  for (int ic = 0; ic < 3; ++ic)
#pragma unroll
    for (int r = 0; r < 4; ++r)
#pragma unroll
      for (int c = 0; c < 4; ++c) {
        const int iy = 2 * py - 1 + r, ix = 2 * px - 1 + c;
        float v = 0.f;
        if (iy >= 0 && iy < 64 && ix >= 0 && ix < 64)
          v = img[(((size_t)b * 3 + ic) * 64 + iy) * 64 + ix];
        patch[ic][r][c] = v;
      }

  float mx = -1e30f;
#pragma unroll
  for (int i = 0; i < 2; ++i)
#pragma unroll
    for (int j = 0; j < 2; ++j) {
      float a = bias;
#pragma unroll
      for (int ic = 0; ic < 3; ++ic)
#pragma unroll
        for (int dy = 0; dy < 3; ++dy)
#pragma unroll
          for (int dx = 0; dx < 3; ++dx)
            a = fmaf(patch[ic][i + dy][j + dx], ws[ic * 9 + dy * 3 + dx], a);
      mx = fmaxf(mx, a);
    }
  out[(((size_t)b * 128 + oc) * 32 + py) * 32 + px] = (bf16_t)fmaxf(mx, 0.f);
}

// ---------------------------------------------------------------------------
// NCHW bf16 -> NHWC bf16
__global__ __launch_bounds__(256) void t1_k(
    const bf16_t* __restrict__ in, bf16_t* __restrict__ out)
{
  const int bid = blockIdx.x;
  const int b = bid >> 4, pt = bid & 15;
  __shared__ bf16_t sT[128][76];
  const int tid = threadIdx.x;
  const int cbase = tid >> 4, px4 = (tid & 15) * 4;
#pragma unroll
  for (int it = 0; it < 8; ++it) {
    const int c = it * 16 + cbase;
    bf16x4 v = *(const bf16x4*)(in + ((size_t)(b * 128 + c)) * 1024 + pt * 64 + px4);
    *(bf16x4*)(&sT[c][px4]) = v;
  }
  __syncthreads();
  const int p = tid >> 2, cg = tid & 3;
#pragma unroll
  for (int vv = 0; vv < 4; ++vv) {
    bf16x8 o;
#pragma unroll
    for (int j = 0; j < 8; ++j) o[j] = sT[cg * 32 + vv * 8 + j][p];
    *(bf16x8*)(out + ((size_t)(b * 1024 + pt * 64 + p)) * 128 + cg * 32 + vv * 8) = o;
  }
}

// ---------------------------------------------------------------------------
// stem2: conv3x3 128->128 on 32x32 NHWC bf16 + relu + maxpool2 -> 16x16 NHWC bf16
__global__ __launch_bounds__(256) void conv_stem2_k(
    const bf16_t* __restrict__ act, const bf16_t* __restrict__ wT,
    const float* __restrict__ bias, bf16_t* __restrict__ out)
{
  const int b = blockIdx.x >> 2, ph = blockIdx.x & 3;
  const int y0 = ph * 8;
  const int tid = threadIdx.x, lane = tid & 63, wv = tid >> 6;
  const int g = lane >> 5, cc = lane & 31;
  const int wq_oc = wv & 1, wq_px = wv >> 1;

  __shared__ bf16_t simg[10 * 34 * 64];

  f32x16 acc[2][4];
#pragma unroll
  for (int i = 0; i < 2; ++i)
#pragma unroll
    for (int j = 0; j < 4; ++j)
#pragma unroll
      for (int r = 0; r < 16; ++r) acc[i][j][r] = 0.f;

  int sl[4];
#pragma unroll
  for (int nf = 0; nf < 4; ++nf) sl[nf] = (wq_px * 4 + nf) * 34 + cc;

  const int ocr0 = wq_oc * 64 + cc;
  const bf16_t* wrow0 = wT + (size_t)ocr0 * 1152;
  const bf16_t* wrow1 = wrow0 + 32 * 1152;

  for (int ich = 0; ich < 2; ++ich) {
    __syncthreads();
    for (int p = tid; p < 340; p += 256) {
      const int yy = p / 34, xx = p - yy * 34;
      const int gy = y0 + yy - 1, gx = xx - 1;
      const bool inb = (gy >= 0 && gy < 32 && gx >= 0 && gx < 32);
      const bf16_t* src = act + ((size_t)(b * 1024 + gy * 32 + gx)) * 128 + ich * 64;
#pragma unroll
      for (int j = 0; j < 8; ++j) {
        bf16x8 v = {};
        if (inb) v = *(const bf16x8*)(src + j * 8);
        const int waddr = (p * 128 + j * 16) ^ ((p & 7) << 4);
        *(bf16x8*)((char*)simg + waddr) = v;
      }
    }
    __syncthreads();

    for (int dydx = 0; dydx < 9; ++dydx) {
      const int dy = dydx / 3, dx = dydx - dy * 3;
      const int sb = dy * 34 + dx;
      const bf16_t* wp0 = wrow0 + dydx * 128 + ich * 64 + g * 8;
      const bf16_t* wp1 = wrow1 + dydx * 128 + ich * 64 + g * 8;
#pragma unroll
      for (int kh = 0; kh < 4; ++kh) {
        const bf16x8 a0 = *(const bf16x8*)(wp0 + kh * 16);
        const bf16x8 a1 = *(const bf16x8*)(wp1 + kh * 16);
#pragma unroll
        for (int nf = 0; nf < 4; ++nf) {
          const int s = sl[nf] + sb;
          const int raddr = (s * 128 + (kh * 2 + g) * 16) ^ ((s & 7) << 4);
          const bf16x8 bb = *(const bf16x8*)((const char*)simg + raddr);
          acc[0][nf] = __builtin_amdgcn_mfma_f32_32x32x16_bf16(a0, bb, acc[0][nf], 0, 0, 0);
          acc[1][nf] = __builtin_amdgcn_mfma_f32_32x32x16_bf16(a1, bb, acc[1][nf], 0, 0, 0);
        }
      }
    }
  }

#pragma unroll
  for (int mf = 0; mf < 2; ++mf) {
#pragma unroll
    for (int q = 0; q < 2; ++q) {
      const int py = (y0 + wq_px * 4 + 2 * q) >> 1;
      const int pxp = cc >> 1;
      bf16_t* op = out + ((size_t)(b * 256 + py * 16 + pxp)) * 128;
#pragma unroll
      for (int rq = 0; rq < 4; ++rq) {
        const int oc4 = wq_oc * 64 + mf * 32 + rq * 8 + g * 4;
        const f32x4 bi = *(const f32x4*)(bias + oc4);
        bf16x4 qv;
#pragma unroll
        for (int j = 0; j < 4; ++j) {
          const int r = rq * 4 + j;
          float v = fmaxf(acc[mf][2 * q][r], acc[mf][2 * q + 1][r]);
          v = fmaxf(v, __shfl_xor(v, 1));
          qv[j] = (bf16_t)fmaxf(v + bi[j], 0.f);
        }
        if ((cc & 1) == 0) *(bf16x4*)(op + oc4) = qv;
      }
    }
  }
}

// ---------------------------------------------------------------------------
// Expert conv3x3 128->128 on 16x16 NHWC bf16.
template<int RES>
__global__ __launch_bounds__(256) void conv_exp_k(
    const bf16_t* __restrict__ act, const bf16_t* __restrict__ wT,
    const float* __restrict__ bias, const int* __restrict__ question, int col,
    const bf16_t* __restrict__ res, bf16_t* __restrict__ out)
{
  const int b = blockIdx.x >> 1, ph = blockIdx.x & 1;
  const int y0 = ph * 8;
  const int e = question[b * 8 + col];
  const int tid = threadIdx.x, lane = tid & 63, wv = tid >> 6;
  const int g = lane >> 5, cc = lane & 31;
  const int wq_oc = wv & 1, wq_px = wv >> 1;

  __shared__ bf16_t simg[10 * 18 * 64];

  f32x16 acc[2][2];
#pragma unroll
  for (int i = 0; i < 2; ++i)
#pragma unroll
    for (int j = 0; j < 2; ++j)
#pragma unroll
      for (int r = 0; r < 16; ++r) acc[i][j][r] = 0.f;

  const int px0 = wq_px * 64 + cc;
  int sl[2];
#pragma unroll
  for (int nf = 0; nf < 2; ++nf) {
    const int px = px0 + nf * 32;
    sl[nf] = (px >> 4) * 18 + (px & 15);
  }

  const bf16_t* wTe = wT + (size_t)e * (128 * 1152);
  const int ocr0 = wq_oc * 64 + cc;
  const bf16_t* wrow0 = wTe + (size_t)ocr0 * 1152;
  const bf16_t* wrow1 = wrow0 + 32 * 1152;

  for (int ich = 0; ich < 2; ++ich) {
    __syncthreads();
    for (int p = tid; p < 180; p += 256) {
      const int yy = p / 18, xx = p - yy * 18;
      const int gy = y0 + yy - 1, gx = xx - 1;
      const bool inb = (gy >= 0 && gy < 16 && gx >= 0 && gx < 16);
      const bf16_t* src = act + ((size_t)(b * 256 + gy * 16 + gx)) * 128 + ich * 64;
#pragma unroll
      for (int j = 0; j < 8; ++j) {
        bf16x8 v = {};
        if (inb) v = *(const bf16x8*)(src + j * 8);
        const int waddr = (p * 128 + j * 16) ^ ((p & 7) << 4);
        *(bf16x8*)((char*)simg + waddr) = v;
      }
    }
    __syncthreads();

    for (int dydx = 0; dydx < 9; ++dydx) {
      const int dy = dydx / 3, dx = dydx - dy * 3;
      const int sb = dy * 18 + dx;
      const bf16_t* wp0 = wrow0 + dydx * 128 + ich * 64 + g * 8;
      const bf16_t* wp1 = wrow1 + dydx * 128 + ich * 64 + g * 8;
#pragma unroll
      for (int kh = 0; kh < 4; ++kh) {
        const bf16x8 a0 = *(const bf16x8*)(wp0 + kh * 16);
        const bf16x8 a1 = *(const bf16x8*)(wp1 + kh * 16);
#pragma unroll
        for (int nf = 0; nf < 2; ++nf) {
          const int s = sl[nf] + sb;
          const int raddr = (s * 128 + (kh * 2 + g) * 16) ^ ((s & 7) << 4);
          const bf16x8 bb = *(const bf16x8*)((const char*)simg + raddr);
          acc[0][nf] = __builtin_amdgcn_mfma_f32_32x32x16_bf16(a0, bb, acc[0][nf], 0, 0, 0);
          acc[1][nf] = __builtin_amdgcn_mfma_f32_32x32x16_bf16(a1, bb, acc[1][nf], 0, 0, 0);
        }
      }
    }
  }

  const float* bb = bias + e * 128;
#pragma unroll
  for (int mf = 0; mf < 2; ++mf) {
#pragma unroll
    for (int nf = 0; nf < 2; ++nf) {
      const int px = px0 + nf * 32;
      const int yl = px >> 4, x = px & 15;
      const size_t pixbase = ((size_t)(b * 256 + (y0 + yl) * 16 + x)) * 128;
      bf16_t* op = out + pixbase;
#pragma unroll
      for (int rq = 0; rq < 4; ++rq) {
        const int oc4 = wq_oc * 64 + mf * 32 + rq * 8 + g * 4;
        const f32x4 bi = *(const f32x4*)(bb + oc4);
        bf16x4 qv;
        bf16x4 rv = {};
        if (RES) rv = *(const bf16x4*)(res + pixbase + oc4);
#pragma unroll
        for (int j = 0; j < 4; ++j) {
          float v = acc[mf][nf][rq * 4 + j] + bi[j];
          if (RES) v += (float)rv[j];
          qv[j] = (bf16_t)fmaxf(v, 0.f);
        }
        *(bf16x4*)(op + oc4) = qv;
      }
    }
  }
}

// ---------------------------------------------------------------------------
// proj 1x1 conv 128->512 + relu + maxpool2, NHWC bf16 in -> f bf16 NCHW (128,512,8,8)
__global__ __launch_bounds__(256) void proj_mfma_k(
    const bf16_t* __restrict__ h, const bf16_t* __restrict__ pw,
    const float* __restrict__ pb, bf16_t* __restrict__ f)
{
  const int b = blockIdx.x >> 2, ocg = blockIdx.x & 3;
  const int tid = threadIdx.x, lane = tid & 63, wv = tid >> 6;
  const int g = lane >> 5, cc = lane & 31;
  const int wq_oc = wv & 1, wq_px = wv >> 1;

  __shared__ bf16_t simg[256 * 64];

  f32x16 acc[2][4];
#pragma unroll
  for (int i = 0; i < 2; ++i)
#pragma unroll
    for (int j = 0; j < 4; ++j)
#pragma unroll
      for (int r = 0; r < 16; ++r) acc[i][j][r] = 0.f;

  const int px0 = wq_px * 128 + cc;
  const int ocr0 = ocg * 128 + wq_oc * 64 + cc;
  const bf16_t* wrow0 = pw + (size_t)ocr0 * 128;
  const bf16_t* wrow1 = wrow0 + 32 * 128;

  for (int ich = 0; ich < 2; ++ich) {
    __syncthreads();
    {
      const int p = tid;
      const bf16_t* src = h + ((size_t)(b * 256 + p)) * 128 + ich * 64;
#pragma unroll
      for (int j = 0; j < 8; ++j) {
        bf16x8 v = *(const bf16x8*)(src + j * 8);
        const int waddr = (p * 128 + j * 16) ^ ((p & 7) << 4);
        *(bf16x8*)((char*)simg + waddr) = v;
      }
    }
    __syncthreads();

#pragma unroll
    for (int kh = 0; kh < 4; ++kh) {
      const bf16x8 a0 = *(const bf16x8*)(wrow0 + ich * 64 + kh * 16 + g * 8);
      const bf16x8 a1 = *(const bf16x8*)(wrow1 + ich * 64 + kh * 16 + g * 8);
#pragma unroll
      for (int nf = 0; nf < 4; ++nf) {
        const int s = px0 + nf * 32;
        const int raddr = (s * 128 + (kh * 2 + g) * 16) ^ ((s & 7) << 4);
        const bf16x8 bb = *(const bf16x8*)((const char*)simg + raddr);
        acc[0][nf] = __builtin_amdgcn_mfma_f32_32x32x16_bf16(a0, bb, acc[0][nf], 0, 0, 0);
        acc[1][nf] = __builtin_amdgcn_mfma_f32_32x32x16_bf16(a1, bb, acc[1][nf], 0, 0, 0);
      }
    }
  }

#pragma unroll
  for (int mf = 0; mf < 2; ++mf) {
#pragma unroll
    for (int nf = 0; nf < 4; ++nf) {
      const int px = px0 + nf * 32;
      const int x = px & 15;
      const int py = wq_px * 4 + nf;
      const int pxp = x >> 1;
#pragma unroll
      for (int r = 0; r < 16; ++r) {
        float v = acc[mf][nf][r];
        v = fmaxf(v, __shfl_xor(v, 1));
        v = fmaxf(v, __shfl_xor(v, 16));
        const int oc = ocg * 128 + wq_oc * 64 + mf * 32 + (r & 3) + 8 * (r >> 2) + 4 * g;
        v = fmaxf(v + pb[oc], 0.f);
        if ((cc & 17) == 0)
          f[((size_t)(b * 512 + oc)) * 64 + py * 8 + pxp] = (bf16_t)v;
      }
    }
  }
}

// ---------------------------------------------------------------------------
// fc1 as bf16 MFMA GEMM: C[m][n] = sum_k A[m][k] * W[n][k]
// A = f bf16 (128 x 32768), W = fc1_w fp32 (1024 x 32768) converted inline.
// grid = (16 n-tiles of 64) x (32 k-slices of 1024); 256 thr = 4 waves (2m x 2n).
__global__ __launch_bounds__(256) void fc1_mfma_k(
    const bf16_t* __restrict__ A, const float* __restrict__ W,
    float* __restrict__ part)
{
  const int nt = blockIdx.x;        // 0..15
  const int ks = blockIdx.y;        // 0..31
  const int n0 = nt * 64;
  const int k0 = ks * 1024;
  const int tid = threadIdx.x, lane = tid & 63, wv = tid >> 6;
  const int g = lane >> 5, cc = lane & 31;
  const int mh = wv & 1, nh = wv >> 1;

  __shared__ char sA[16384];   // [128][64] bf16, XOR-swizzled
  __shared__ char sB[8192];    // [64][64] bf16, XOR-swizzled

  f32x16 acc0, acc1;
#pragma unroll
  for (int r = 0; r < 16; ++r) { acc0[r] = 0.f; acc1[r] = 0.f; }

  for (int t = 0; t < 16; ++t) {   // 16 K-tiles of 64
    __syncthreads();
    // stage A tile [128 m][64 k] bf16 (16 KB)
#pragma unroll
    for (int i = 0; i < 4; ++i) {
      const int c = tid + i * 256;           // 1024 chunks of 16 B
      const int row = c >> 3, ko = c & 7;
      bf16x8 v = *(const bf16x8*)(A + (size_t)row * 32768 + k0 + t * 64 + ko * 8);
      const int wa = (row * 128 + ko * 16) ^ ((row & 7) << 4);
      *(bf16x8*)(sA + wa) = v;
    }
    // stage B tile [64 n][64 k]: fp32 global -> bf16 LDS
#pragma unroll
    for (int i = 0; i < 2; ++i) {
      const int c = tid + i * 256;           // 512 chunks of 16 B (8 elems)
      const int row = c >> 3, ko = c & 7;
      const float* src = W + (size_t)(n0 + row) * 32768 + k0 + t * 64 + ko * 8;
      f32x4 u0 = *(const f32x4*)src;
      f32x4 u1 = *(const f32x4*)(src + 4);
      bf16x8 v;
#pragma unroll
      for (int j = 0; j < 4; ++j) { v[j] = (bf16_t)u0[j]; v[4 + j] = (bf16_t)u1[j]; }
      const int wa = (row * 128 + ko * 16) ^ ((row & 7) << 4);
      *(bf16x8*)(sB + wa) = v;
    }
    __syncthreads();
#pragma unroll
    for (int kss = 0; kss < 4; ++kss) {
      const int kb = kss * 32 + g * 16;      // k byte offset in row
      const int rA0 = mh * 64 + cc, rA1 = rA0 + 32;
      const bf16x8 a0 = *(const bf16x8*)(sA + ((rA0 * 128 + kb) ^ ((rA0 & 7) << 4)));
      const bf16x8 a1 = *(const bf16x8*)(sA + ((rA1 * 128 + kb) ^ ((rA1 & 7) << 4)));
      const int rB = nh * 32 + cc;
      const bf16x8 bb = *(const bf16x8*)(sB + ((rB * 128 + kb) ^ ((rB & 7) << 4)));
      acc0 = __builtin_amdgcn_mfma_f32_32x32x16_bf16(a0, bb, acc0, 0, 0, 0);
      acc1 = __builtin_amdgcn_mfma_f32_32x32x16_bf16(a1, bb, acc1, 0, 0, 0);
    }
  }

  float* pp = part + ((size_t)ks * 128) * 1024 + n0 + nh * 32 + cc;
#pragma unroll
  for (int r = 0; r < 16; ++r) {
    const int m0 = mh * 64 + (r & 3) + 8 * (r >> 2) + 4 * g;
    pp[(size_t)m0 * 1024] = acc0[r];
    pp[(size_t)(m0 + 32) * 1024] = acc1[r];
  }
}

__global__ __launch_bounds__(256) void fc1_red_k(
    const float* __restrict__ part, const float* __restrict__ bias, float* __restrict__ fo)
{
  const int i = blockIdx.x * 256 + threadIdx.x;   // 131072
  const int m = i >> 10, j = i & 1023;
  float s = bias[j];
#pragma unroll
  for (int ks = 0; ks < 32; ++ks) s += part[((size_t)ks * 128 + m) * 1024 + j];
  fo[i] = fmaxf(s, 0.f);
}

// ---------------------------------------------------------------------------
__global__ __launch_bounds__(256) void fc2_k(
    const float* __restrict__ fo, const float* __restrict__ w2,
    const float* __restrict__ b2, float* __restrict__ out)
{
  const int m = blockIdx.x;
  const int tid = threadIdx.x;
  float a0 = 0.f, a1 = 0.f;
  for (int k = tid; k < 1024; k += 256) {
    const float fv = fo[(size_t)m * 1024 + k];
    a0 = fmaf(fv, w2[k], a0);
    a1 = fmaf(fv, w2[1024 + k], a1);
  }
#pragma unroll
  for (int o = 32; o > 0; o >>= 1) {
    a0 += __shfl_down(a0, o);
    a1 += __shfl_down(a1, o);
  }
  __shared__ float r0[4], r1[4];
  const int wid = tid >> 6;
  if ((tid & 63) == 0) { r0[wid] = a0; r1[wid] = a1; }
  __syncthreads();
  if (tid == 0) {
    out[(size_t)m * 2 + 0] = r0[0] + r0[1] + r0[2] + r0[3] + b2[0];
    out[(size_t)m * 2 + 1] = r1[0] + r1[1] + r1[2] + r1[3] + b2[1];
  }
}

// ---------------------------------------------------------------------------
extern "C" void kernel_launch(void* const* d_in, const int* in_sizes, int n_in,
                              void* d_out, int out_size, void* d_ws, size_t ws_size,
                              hipStream_t stream)
{
  const float* image    = (const float*)d_in[0];
  const int*   question = (const int*)  d_in[1];
  const float* stem_w1  = (const float*)d_in[2];
  const float* stem_b1  = (const float*)d_in[3];
  const float* stem_w2  = (const float*)d_in[4];
  const float* stem_b2  = (const float*)d_in[5];
  const float* exp_w1   = (const float*)d_in[6];
  const float* exp_b1   = (const float*)d_in[7];
  const float* exp_w2   = (const float*)d_in[8];
  const float* exp_b2   = (const float*)d_in[9];
  const float* proj_w   = (const float*)d_in[10];
  const float* proj_b   = (const float*)d_in[11];
  const float* fc1_w    = (const float*)d_in[12];
  const float* fc1_b    = (const float*)d_in[13];
  const float* fc2_w    = (const float*)d_in[14];
  const float* fc2_b    = (const float*)d_in[15];
  float* out = (float*)d_out;

  char* base = (char*)d_ws;
  bf16_t* stem1o = (bf16_t*)base;                      // 33,554,432 B (early)
  bf16_t* actA   = (bf16_t*)(base + 33554432);         // 33,554,432 B (NHWC 32x32)
  bf16_t* actH   = (bf16_t*)(base + 67108864);         //  8,388,608 B (NHWC 16x16)
  bf16_t* actT   = (bf16_t*)(base + 75497472);         //  8,388,608 B
  bf16_t* wT1    = (bf16_t*)(base + 83886080);         //  4,718,592 B
  bf16_t* wT2    = (bf16_t*)(base + 88604672);         //  4,718,592 B
  bf16_t* wTs2   = (bf16_t*)(base + 93323264);         //    294,912 B
  bf16_t* pwT    = (bf16_t*)(base + 93618176);         //    131,072 B
  // region0 reuse (after stem1o consumed): f bf16, fc1 partials, fc1 out
  bf16_t* fbf  = (bf16_t*)base;                        //  8,388,608 B
  float*  part = (float*)(base + 8388608);             // 16,777,216 B (32x128x1024)
  float*  f1o  = (float*)(base + 25165824);            //    524,288 B

  // weight prep
  wconv_k<<<2048, 256, 0, stream>>>(exp_w1, wT1);
  wconv_k<<<2048, 256, 0, stream>>>(exp_w2, wT2);
  wconv_k<<<128, 256, 0, stream>>>(stem_w2, wTs2);
  pconv_k<<<256, 256, 0, stream>>>(proj_w, pwT);

  // stem
  stem1_k<<<dim3(512, 128), 256, 0, stream>>>(image, stem_w1, stem_b1, stem1o);
  t1_k<<<2048, 256, 0, stream>>>(stem1o, actA);
  conv_stem2_k<<<512, 256, 0, stream>>>(actA, wTs2, stem_b2, actH);

  // expert residual blocks, routing cols (3,4,6,7,5)
  const int cols[5] = {3, 4, 6, 7, 5};
  for (int i = 0; i < 5; ++i) {
    conv_exp_k<0><<<256, 256, 0, stream>>>(actH, wT1, exp_b1, question, cols[i],
                                           nullptr, actT);
    conv_exp_k<1><<<256, 256, 0, stream>>>(actT, wT2, exp_b2, question, cols[i],
                                           actH, actH);
  }

  // head
  proj_mfma_k<<<512, 256, 0, stream>>>(actH, pwT, proj_b, fbf);
  fc1_mfma_k<<<dim3(16, 32), 256, 0, stream>>>(fbf, fc1_w, part);
  fc1_red_k<<<512, 256, 0, stream>>>(part, fc1_b, f1o);
  fc2_k<<<128, 256, 0, stream>>>(f1o, fc2_w, fc2_b, out);
}

// Round 6
// 477.115 us; speedup vs baseline: 12.3311x; 1.5390x over previous
//
#include <hip/hip_runtime.h>
#include <hip/hip_bf16.h>
#include <cstdint>
#include <cstddef>

// SimpleModuleNet MoE CNN forward — bf16 MFMA implicit-GEMM version.
// B=128, C=128, E=16, H=W=64, PROJ=512, FC=1024, NANS=2
//
// Conv formulation: out[oc][px] = sum_k w[oc][k] * in_patch[k][px], k=(ic,dy,dx),
// decomposed per (dy,dx). MFMA v_mfma_f32_32x32x16_bf16; A,B fragments use the
// SAME slot convention k = (lane>>5)*8 + j  => any k-permutation cancels.
// C/D layout (HW-verified): col = lane&31, row = (r&3)+8*(r>>2)+4*(lane>>5).

typedef __bf16 bf16_t;
typedef __attribute__((ext_vector_type(4))) bf16_t bf16x4;
typedef __attribute__((ext_vector_type(8))) bf16_t bf16x8;
typedef __attribute__((ext_vector_type(16))) float f32x16;
typedef __attribute__((ext_vector_type(4))) float f32x4;

// ---------------------------------------------------------------------------
// Weight transform: [R rows][128 ic][3][3] fp32 -> [R][9 dydx][128 ic] bf16
__global__ __launch_bounds__(256) void wconv_k(
    const float* __restrict__ in, bf16_t* __restrict__ out)
{
  const int r = blockIdx.x;
  const float* ip = in + (size_t)r * 1152;
  bf16_t* op = out + (size_t)r * 1152;
  for (int t = threadIdx.x; t < 1152; t += 256) {
    const int dd = t >> 7, ic = t & 127;
    op[t] = (bf16_t)ip[ic * 9 + dd];
  }
}

// proj weights [512][128] fp32 -> bf16
__global__ __launch_bounds__(256) void pconv_k(
    const float* __restrict__ in, bf16_t* __restrict__ out)
{
  const int i = blockIdx.x * 256 + threadIdx.x;
  out[i] = (bf16_t)in[i];
}

// ---------------------------------------------------------------------------
// stem1 fused: conv3x3 (3->128, 64x64, pad1) + relu + maxpool2 -> NHWC bf16
// (128, 32x32 px, 128 ch) DIRECTLY (no NCHW intermediate, no transpose pass).
// Block = one 8x8 pooled tile of one image; image patch (3 x 18x18) staged in
// LDS ONCE (vs once-per-oc before = 128x fewer loads). Lanes = 64 pooled px,
// warp w handles oc [32w, 32w+32): weights wave-uniform -> scalar s_loads.
__global__ __launch_bounds__(256) void stem1_nhwc_k(
    const float* __restrict__ img, const float* __restrict__ w1,
    const float* __restrict__ b1, bf16_t* __restrict__ out)
{
  const int bid = blockIdx.x;            // 128 b * 16 tiles
  const int b = bid >> 4, t = bid & 15;
  const int ty0p = (t >> 2) * 8, tx0p = (t & 3) * 8;   // pooled tile origin
  const int tid = threadIdx.x, lane = tid & 63;
  const int wvbase = __builtin_amdgcn_readfirstlane(tid >> 6) * 32;

  __shared__ float sImg[3][18][19];      // conv-input patch with halo, +1 pad
  __shared__ char  sOut[16384];          // [64 px][128 oc] bf16, XOR-swizzled

  // stage image patch: rows 2*ty0p-1 .. +16, cols 2*tx0p-1 .. +16, zero-pad
  for (int s = tid; s < 972; s += 256) {
    const int ic = s / 324, r2 = s - ic * 324;
    const int rr = r2 / 18, cc = r2 - rr * 18;
    const int gy = 2 * ty0p - 1 + rr, gx = 2 * tx0p - 1 + cc;
    float v = 0.f;
    if (gy >= 0 && gy < 64 && gx >= 0 && gx < 64)
      v = img[(((size_t)b * 3 + ic) * 64 + gy) * 64 + gx];
    sImg[ic][rr][cc] = v;
  }
  __syncthreads();

  // per-thread 4x4x3 patch (the 2x2 conv window feeding one pooled px)
  const int ppy = lane >> 3, ppx = lane & 7;
  float patch[3][4][4];
#pragma unroll
  for (int ic = 0; ic < 3; ++ic)
#pragma unroll
    for (int r = 0; r < 4; ++r)
#pragma unroll
      for (int c = 0; c < 4; ++c)
        patch[ic][r][c] = sImg[ic][2 * ppy + r][2 * ppx + c];

  const int swz = (lane & 15) << 3;
  char* orow = sOut + lane * 256;
#pragma unroll 2
  for (int o4 = 0; o4 < 32; o4 += 4) {
    bf16x4 qv;
#pragma unroll
    for (int j = 0; j < 4; ++j) {
      const int oc = wvbase + o4 + j;
      const float* wp = w1 + oc * 27;      // wave-uniform -> s_load
      float a[2][2];
#pragma unroll
      for (int i = 0; i < 2; ++i)
#pragma unroll
        for (int jj = 0; jj < 2; ++jj) a[i][jj] = b1[oc];
#pragma unroll
      for (int ic = 0; ic < 3; ++ic)
#pragma unroll
        for (int dy = 0; dy < 3; ++dy)
#pragma unroll
          for (int dx = 0; dx < 3; ++dx) {
            const float wv = wp[ic * 9 + dy * 3 + dx];
#pragma unroll
            for (int i = 0; i < 2; ++i)
#pragma unroll
              for (int jj = 0; jj < 2; ++jj)
                a[i][jj] = fmaf(patch[ic][i + dy][jj + dx], wv, a[i][jj]);
          }
      const float mx = fmaxf(fmaxf(a[0][0], a[0][1]), fmaxf(a[1][0], a[1][1]));
      qv[j] = (bf16_t)fmaxf(mx, 0.f);
    }
    *(bf16x4*)(orow + (((wvbase + o4) * 2) ^ swz)) = qv;
  }
  __syncthreads();

  // cooperative NHWC write: 64 px * 256 B, coalesced 16B/lane
#pragma unroll
  for (int it = 0; it < 4; ++it) {
    const int idx = it * 256 + tid;
    const int px = idx >> 4, ch8 = idx & 15;
    const int sw = (px & 15) << 3;
    const char* rb = sOut + px * 256;
    bf16x4 lo = *(const bf16x4*)(rb + ((ch8 * 16) ^ sw));
    bf16x4 hi = *(const bf16x4*)(rb + ((ch8 * 16 + 8) ^ sw));
    bf16x8 v;
#pragma unroll
    for (int j = 0; j < 4; ++j) { v[j] = lo[j]; v[4 + j] = hi[j]; }
    const int gpy = ty0p + (px >> 3), gpx = tx0p + (px & 7);
    *(bf16x8*)(out + ((size_t)(b * 1024 + gpy * 32 + gpx)) * 128 + ch8 * 8) = v;
  }
}

// ---------------------------------------------------------------------------
// stem2: conv3x3 128->128 on 32x32 NHWC bf16 + relu + maxpool2 -> 16x16 NHWC bf16
__global__ __launch_bounds__(256) void conv_stem2_k(
    const bf16_t* __restrict__ act, const bf16_t* __restrict__ wT,
    const float* __restrict__ bias, bf16_t* __restrict__ out)
{
  const int b = blockIdx.x >> 2, ph = blockIdx.x & 3;
  const int y0 = ph * 8;
  const int tid = threadIdx.x, lane = tid & 63, wv = tid >> 6;
  const int g = lane >> 5, cc = lane & 31;
  const int wq_oc = wv & 1, wq_px = wv >> 1;

  __shared__ bf16_t simg[10 * 34 * 64];

  f32x16 acc[2][4];
#pragma unroll
  for (int i = 0; i < 2; ++i)
#pragma unroll
    for (int j = 0; j < 4; ++j)
#pragma unroll
      for (int r = 0; r < 16; ++r) acc[i][j][r] = 0.f;

  int sl[4];
#pragma unroll
  for (int nf = 0; nf < 4; ++nf) sl[nf] = (wq_px * 4 + nf) * 34 + cc;

  const int ocr0 = wq_oc * 64 + cc;
  const bf16_t* wrow0 = wT + (size_t)ocr0 * 1152;
  const bf16_t* wrow1 = wrow0 + 32 * 1152;

  for (int ich = 0; ich < 2; ++ich) {
    __syncthreads();
    for (int p = tid; p < 340; p += 256) {
      const int yy = p / 34, xx = p - yy * 34;
      const int gy = y0 + yy - 1, gx = xx - 1;
      const bool inb = (gy >= 0 && gy < 32 && gx >= 0 && gx < 32);
      const bf16_t* src = act + ((size_t)(b * 1024 + gy * 32 + gx)) * 128 + ich * 64;
#pragma unroll
      for (int j = 0; j < 8; ++j) {
        bf16x8 v = {};
        if (inb) v = *(const bf16x8*)(src + j * 8);
        const int waddr = (p * 128 + j * 16) ^ ((p & 7) << 4);
        *(bf16x8*)((char*)simg + waddr) = v;
      }
    }
    __syncthreads();

    for (int dydx = 0; dydx < 9; ++dydx) {
      const int dy = dydx / 3, dx = dydx - dy * 3;
      const int sb = dy * 34 + dx;
      const bf16_t* wp0 = wrow0 + dydx * 128 + ich * 64 + g * 8;
      const bf16_t* wp1 = wrow1 + dydx * 128 + ich * 64 + g * 8;
#pragma unroll
      for (int kh = 0; kh < 4; ++kh) {
        const bf16x8 a0 = *(const bf16x8*)(wp0 + kh * 16);
        const bf16x8 a1 = *(const bf16x8*)(wp1 + kh * 16);
#pragma unroll
        for (int nf = 0; nf < 4; ++nf) {
          const int s = sl[nf] + sb;
          const int raddr = (s * 128 + (kh * 2 + g) * 16) ^ ((s & 7) << 4);
          const bf16x8 bb = *(const bf16x8*)((const char*)simg + raddr);
          acc[0][nf] = __builtin_amdgcn_mfma_f32_32x32x16_bf16(a0, bb, acc[0][nf], 0, 0, 0);
          acc[1][nf] = __builtin_amdgcn_mfma_f32_32x32x16_bf16(a1, bb, acc[1][nf], 0, 0, 0);
        }
      }
    }
  }

#pragma unroll
  for (int mf = 0; mf < 2; ++mf) {
#pragma unroll
    for (int q = 0; q < 2; ++q) {
      const int py = (y0 + wq_px * 4 + 2 * q) >> 1;
      const int pxp = cc >> 1;
      bf16_t* op = out + ((size_t)(b * 256 + py * 16 + pxp)) * 128;
#pragma unroll
      for (int rq = 0; rq < 4; ++rq) {
        const int oc4 = wq_oc * 64 + mf * 32 + rq * 8 + g * 4;
        const f32x4 bi = *(const f32x4*)(bias + oc4);
        bf16x4 qv;
#pragma unroll
        for (int j = 0; j < 4; ++j) {
          const int r = rq * 4 + j;
          float v = fmaxf(acc[mf][2 * q][r], acc[mf][2 * q + 1][r]);
          v = fmaxf(v, __shfl_xor(v, 1));
          qv[j] = (bf16_t)fmaxf(v + bi[j], 0.f);
        }
        if ((cc & 1) == 0) *(bf16x4*)(op + oc4) = qv;
      }
    }
  }
}

// ---------------------------------------------------------------------------
// Expert conv3x3 128->128 on 16x16 NHWC bf16.
template<int RES>
__global__ __launch_bounds__(256) void conv_exp_k(
    const bf16_t* __restrict__ act, const bf16_t* __restrict__ wT,
    const float* __restrict__ bias, const int* __restrict__ question, int col,
    const bf16_t* __restrict__ res, bf16_t* __restrict__ out)
{
  const int b = blockIdx.x >> 1, ph = blockIdx.x & 1;
  const int y0 = ph * 8;
  const int e = question[b * 8 + col];
  const int tid = threadIdx.x, lane = tid & 63, wv = tid >> 6;
  const int g = lane >> 5, cc = lane & 31;
  const int wq_oc = wv & 1, wq_px = wv >> 1;

  __shared__ bf16_t simg[10 * 18 * 64];

  f32x16 acc[2][2];
#pragma unroll
  for (int i = 0; i < 2; ++i)
#pragma unroll
    for (int j = 0; j < 2; ++j)
#pragma unroll
      for (int r = 0; r < 16; ++r) acc[i][j][r] = 0.f;

  const int px0 = wq_px * 64 + cc;
  int sl[2];
#pragma unroll
  for (int nf = 0; nf < 2; ++nf) {
    const int px = px0 + nf * 32;
    sl[nf] = (px >> 4) * 18 + (px & 15);
  }

  const bf16_t* wTe = wT + (size_t)e * (128 * 1152);
  const int ocr0 = wq_oc * 64 + cc;
  const bf16_t* wrow0 = wTe + (size_t)ocr0 * 1152;
  const bf16_t* wrow1 = wrow0 + 32 * 1152;

  for (int ich = 0; ich < 2; ++ich) {
    __syncthreads();
    for (int p = tid; p < 180; p += 256) {
      const int yy = p / 18, xx = p - yy * 18;
      const int gy = y0 + yy - 1, gx = xx - 1;
      const bool inb = (gy >= 0 && gy < 16 && gx >= 0 && gx < 16);
      const bf16_t* src = act + ((size_t)(b * 256 + gy * 16 + gx)) * 128 + ich * 64;
#pragma unroll
      for (int j = 0; j < 8; ++j) {
        bf16x8 v = {};
        if (inb) v = *(const bf16x8*)(src + j * 8);
        const int waddr = (p * 128 + j * 16) ^ ((p & 7) << 4);
        *(bf16x8*)((char*)simg + waddr) = v;
      }
    }
    __syncthreads();

    for (int dydx = 0; dydx < 9; ++dydx) {
      const int dy = dydx / 3, dx = dydx - dy * 3;
      const int sb = dy * 18 + dx;
      const bf16_t* wp0 = wrow0 + dydx * 128 + ich * 64 + g * 8;
      const bf16_t* wp1 = wrow1 + dydx * 128 + ich * 64 + g * 8;
#pragma unroll
      for (int kh = 0; kh < 4; ++kh) {
        const bf16x8 a0 = *(const bf16x8*)(wp0 + kh * 16);
        const bf16x8 a1 = *(const bf16x8*)(wp1 + kh * 16);
#pragma unroll
        for (int nf = 0; nf < 2; ++nf) {
          const int s = sl[nf] + sb;
          const int raddr = (s * 128 + (kh * 2 + g) * 16) ^ ((s & 7) << 4);
          const bf16x8 bb = *(const bf16x8*)((const char*)simg + raddr);
          acc[0][nf] = __builtin_amdgcn_mfma_f32_32x32x16_bf16(a0, bb, acc[0][nf], 0, 0, 0);
          acc[1][nf] = __builtin_amdgcn_mfma_f32_32x32x16_bf16(a1, bb, acc[1][nf], 0, 0, 0);
        }
      }
    }
  }

  const float* bb = bias + e * 128;
#pragma unroll
  for (int mf = 0; mf < 2; ++mf) {
#pragma unroll
    for (int nf = 0; nf < 2; ++nf) {
      const int px = px0 + nf * 32;
      const int yl = px >> 4, x = px & 15;
      const size_t pixbase = ((size_t)(b * 256 + (y0 + yl) * 16 + x)) * 128;
      bf16_t* op = out + pixbase;
#pragma unroll
      for (int rq = 0; rq < 4; ++rq) {
        const int oc4 = wq_oc * 64 + mf * 32 + rq * 8 + g * 4;
        const f32x4 bi = *(const f32x4*)(bb + oc4);
        bf16x4 qv;
        bf16x4 rv = {};
        if (RES) rv = *(const bf16x4*)(res + pixbase + oc4);
#pragma unroll
        for (int j = 0; j < 4; ++j) {
          float v = acc[mf][nf][rq * 4 + j] + bi[j];
          if (RES) v += (float)rv[j];
          qv[j] = (bf16_t)fmaxf(v, 0.f);
        }
        *(bf16x4*)(op + oc4) = qv;
      }
    }
  }
}

// ---------------------------------------------------------------------------
// proj 1x1 conv 128->512 + relu + maxpool2, NHWC bf16 in -> f bf16 NCHW (128,512,8,8)
__global__ __launch_bounds__(256) void proj_mfma_k(
    const bf16_t* __restrict__ h, const bf16_t* __restrict__ pw,
    const float* __restrict__ pb, bf16_t* __restrict__ f)
{
  const int b = blockIdx.x >> 2, ocg = blockIdx.x & 3;
  const int tid = threadIdx.x, lane = tid & 63, wv = tid >> 6;
  const int g = lane >> 5, cc = lane & 31;
  const int wq_oc = wv & 1, wq_px = wv >> 1;

  __shared__ bf16_t simg[256 * 64];

  f32x16 acc[2][4];
#pragma unroll
  for (int i = 0; i < 2; ++i)
#pragma unroll
    for (int j = 0; j < 4; ++j)
#pragma unroll
      for (int r = 0; r < 16; ++r) acc[i][j][r] = 0.f;

  const int px0 = wq_px * 128 + cc;
  const int ocr0 = ocg * 128 + wq_oc * 64 + cc;
  const bf16_t* wrow0 = pw + (size_t)ocr0 * 128;
  const bf16_t* wrow1 = wrow0 + 32 * 128;

  for (int ich = 0; ich < 2; ++ich) {
    __syncthreads();
    {
      const int p = tid;
      const bf16_t* src = h + ((size_t)(b * 256 + p)) * 128 + ich * 64;
#pragma unroll
      for (int j = 0; j < 8; ++j) {
        bf16x8 v = *(const bf16x8*)(src + j * 8);
        const int waddr = (p * 128 + j * 16) ^ ((p & 7) << 4);
        *(bf16x8*)((char*)simg + waddr) = v;
      }
    }
    __syncthreads();

#pragma unroll
    for (int kh = 0; kh < 4; ++kh) {
      const bf16x8 a0 = *(const bf16x8*)(wrow0 + ich * 64 + kh * 16 + g * 8);
      const bf16x8 a1 = *(const bf16x8*)(wrow1 + ich * 64 + kh * 16 + g * 8);
#pragma unroll
      for (int nf = 0; nf < 4; ++nf) {
        const int s = px0 + nf * 32;
        const int raddr = (s * 128 + (kh * 2 + g) * 16) ^ ((s & 7) << 4);
        const bf16x8 bb = *(const bf16x8*)((const char*)simg + raddr);
        acc[0][nf] = __builtin_amdgcn_mfma_f32_32x32x16_bf16(a0, bb, acc[0][nf], 0, 0, 0);
        acc[1][nf] = __builtin_amdgcn_mfma_f32_32x32x16_bf16(a1, bb, acc[1][nf], 0, 0, 0);
      }
    }
  }

#pragma unroll
  for (int mf = 0; mf < 2; ++mf) {
#pragma unroll
    for (int nf = 0; nf < 4; ++nf) {
      const int px = px0 + nf * 32;
      const int x = px & 15;
      const int py = wq_px * 4 + nf;
      const int pxp = x >> 1;
#pragma unroll
      for (int r = 0; r < 16; ++r) {
        float v = acc[mf][nf][r];
        v = fmaxf(v, __shfl_xor(v, 1));
        v = fmaxf(v, __shfl_xor(v, 16));
        const int oc = ocg * 128 + wq_oc * 64 + mf * 32 + (r & 3) + 8 * (r >> 2) + 4 * g;
        v = fmaxf(v + pb[oc], 0.f);
        if ((cc & 17) == 0)
          f[((size_t)(b * 512 + oc)) * 64 + py * 8 + pxp] = (bf16_t)v;
      }
    }
  }
}

// ---------------------------------------------------------------------------
// fc1 as bf16 MFMA GEMM: C[m][n] = sum_k A[m][k] * W[n][k]
// A = f bf16 (128 x 32768), W = fc1_w fp32 (1024 x 32768) converted inline.
// grid = (16 n-tiles of 64) x (32 k-slices of 1024); 256 thr = 4 waves (2m x 2n).
__global__ __launch_bounds__(256) void fc1_mfma_k(
    const bf16_t* __restrict__ A, const float* __restrict__ W,
    float* __restrict__ part)
{
  const int nt = blockIdx.x;        // 0..15
  const int ks = blockIdx.y;        // 0..31
  const int n0 = nt * 64;
  const int k0 = ks * 1024;
  const int tid = threadIdx.x, lane = tid & 63, wv = tid >> 6;
  const int g = lane >> 5, cc = lane & 31;
  const int mh = wv & 1, nh = wv >> 1;

  __shared__ char sA[16384];   // [128][64] bf16, XOR-swizzled
  __shared__ char sB[8192];    // [64][64] bf16, XOR-swizzled

  f32x16 acc0, acc1;
#pragma unroll
  for (int r = 0; r < 16; ++r) { acc0[r] = 0.f; acc1[r] = 0.f; }

  for (int t = 0; t < 16; ++t) {   // 16 K-tiles of 64
    __syncthreads();
    // stage A tile [128 m][64 k] bf16 (16 KB)
#pragma unroll
    for (int i = 0; i < 4; ++i) {
      const int c = tid + i * 256;           // 1024 chunks of 16 B
      const int row = c >> 3, ko = c & 7;
      bf16x8 v = *(const bf16x8*)(A + (size_t)row * 32768 + k0 + t * 64 + ko * 8);
      const int wa = (row * 128 + ko * 16) ^ ((row & 7) << 4);
      *(bf16x8*)(sA + wa) = v;
    }
    // stage B tile [64 n][64 k]: fp32 global -> bf16 LDS
#pragma unroll
    for (int i = 0; i < 2; ++i) {
      const int c = tid + i * 256;           // 512 chunks of 16 B (8 elems)
      const int row = c >> 3, ko = c & 7;
      const float* src = W + (size_t)(n0 + row) * 32768 + k0 + t * 64 + ko * 8;
      f32x4 u0 = *(const f32x4*)src;
      f32x4 u1 = *(const f32x4*)(src + 4);
      bf16x8 v;
#pragma unroll
      for (int j = 0; j < 4; ++j) { v[j] = (bf16_t)u0[j]; v[4 + j] = (bf16_t)u1[j]; }
      const int wa = (row * 128 + ko * 16) ^ ((row & 7) << 4);
      *(bf16x8*)(sB + wa) = v;
    }
    __syncthreads();
#pragma unroll
    for (int kss = 0; kss < 4; ++kss) {
      const int kb = kss * 32 + g * 16;      // k byte offset in row
      const int rA0 = mh * 64 + cc, rA1 = rA0 + 32;
      const bf16x8 a0 = *(const bf16x8*)(sA + ((rA0 * 128 + kb) ^ ((rA0 & 7) << 4)));
      const bf16x8 a1 = *(const bf16x8*)(sA + ((rA1 * 128 + kb) ^ ((rA1 & 7) << 4)));
      const int rB = nh * 32 + cc;
      const bf16x8 bb = *(const bf16x8*)(sB + ((rB * 128 + kb) ^ ((rB & 7) << 4)));
      acc0 = __builtin_amdgcn_mfma_f32_32x32x16_bf16(a0, bb, acc0, 0, 0, 0);
      acc1 = __builtin_amdgcn_mfma_f32_32x32x16_bf16(a1, bb, acc1, 0, 0, 0);
    }
  }

  float* pp = part + ((size_t)ks * 128) * 1024 + n0 + nh * 32 + cc;
#pragma unroll
  for (int r = 0; r < 16; ++r) {
    const int m0 = mh * 64 + (r & 3) + 8 * (r >> 2) + 4 * g;
    pp[(size_t)m0 * 1024] = acc0[r];
    pp[(size_t)(m0 + 32) * 1024] = acc1[r];
  }
}

__global__ __launch_bounds__(256) void fc1_red_k(
    const float* __restrict__ part, const float* __restrict__ bias, float* __restrict__ fo)
{
  const int i = blockIdx.x * 256 + threadIdx.x;   // 131072
  const int m = i >> 10, j = i & 1023;
  float s = bias[j];
#pragma unroll
  for (int ks = 0; ks < 32; ++ks) s += part[((size_t)ks * 128 + m) * 1024 + j];
  fo[i] = fmaxf(s, 0.f);
}

// ---------------------------------------------------------------------------
__global__ __launch_bounds__(256) void fc2_k(
    const float* __restrict__ fo, const float* __restrict__ w2,
    const float* __restrict__ b2, float* __restrict__ out)
{
  const int m = blockIdx.x;
  const int tid = threadIdx.x;
  float a0 = 0.f, a1 = 0.f;
  for (int k = tid; k < 1024; k += 256) {
    const float fv = fo[(size_t)m * 1024 + k];
    a0 = fmaf(fv, w2[k], a0);
    a1 = fmaf(fv, w2[1024 + k], a1);
  }
#pragma unroll
  for (int o = 32; o > 0; o >>= 1) {
    a0 += __shfl_down(a0, o);
    a1 += __shfl_down(a1, o);
  }
  __shared__ float r0[4], r1[4];
  const int wid = tid >> 6;
  if ((tid & 63) == 0) { r0[wid] = a0; r1[wid] = a1; }
  __syncthreads();
  if (tid == 0) {
    out[(size_t)m * 2 + 0] = r0[0] + r0[1] + r0[2] + r0[3] + b2[0];
    out[(size_t)m * 2 + 1] = r1[0] + r1[1] + r1[2] + r1[3] + b2[1];
  }
}

// ---------------------------------------------------------------------------
extern "C" void kernel_launch(void* const* d_in, const int* in_sizes, int n_in,
                              void* d_out, int out_size, void* d_ws, size_t ws_size,
                              hipStream_t stream)
{
  const float* image    = (const float*)d_in[0];
  const int*   question = (const int*)  d_in[1];
  const float* stem_w1  = (const float*)d_in[2];
  const float* stem_b1  = (const float*)d_in[3];
  const float* stem_w2  = (const float*)d_in[4];
  const float* stem_b2  = (const float*)d_in[5];
  const float* exp_w1   = (const float*)d_in[6];
  const float* exp_b1   = (const float*)d_in[7];
  const float* exp_w2   = (const float*)d_in[8];
  const float* exp_b2   = (const float*)d_in[9];
  const float* proj_w   = (const float*)d_in[10];
  const float* proj_b   = (const float*)d_in[11];
  const float* fc1_w    = (const float*)d_in[12];
  const float* fc1_b    = (const float*)d_in[13];
  const float* fc2_w    = (const float*)d_in[14];
  const float* fc2_b    = (const float*)d_in[15];
  float* out = (float*)d_out;

  char* base = (char*)d_ws;
  bf16_t* actA   = (bf16_t*)(base + 33554432);         // 33,554,432 B (NHWC 32x32)
  bf16_t* actH   = (bf16_t*)(base + 67108864);         //  8,388,608 B (NHWC 16x16)
  bf16_t* actT   = (bf16_t*)(base + 75497472);         //  8,388,608 B
  bf16_t* wT1    = (bf16_t*)(base + 83886080);         //  4,718,592 B
  bf16_t* wT2    = (bf16_t*)(base + 88604672);         //  4,718,592 B
  bf16_t* wTs2   = (bf16_t*)(base + 93323264);         //    294,912 B
  bf16_t* pwT    = (bf16_t*)(base + 93618176);         //    131,072 B
  // region0 reuse: f bf16, fc1 partials, fc1 out
  bf16_t* fbf  = (bf16_t*)base;                        //  8,388,608 B
  float*  part = (float*)(base + 8388608);             // 16,777,216 B (32x128x1024)
  float*  f1o  = (float*)(base + 25165824);            //    524,288 B

  // weight prep
  wconv_k<<<2048, 256, 0, stream>>>(exp_w1, wT1);
  wconv_k<<<2048, 256, 0, stream>>>(exp_w2, wT2);
  wconv_k<<<128, 256, 0, stream>>>(stem_w2, wTs2);
  pconv_k<<<256, 256, 0, stream>>>(proj_w, pwT);

  // stem (fused conv+relu+pool -> NHWC directly; no transpose pass)
  stem1_nhwc_k<<<2048, 256, 0, stream>>>(image, stem_w1, stem_b1, actA);
  conv_stem2_k<<<512, 256, 0, stream>>>(actA, wTs2, stem_b2, actH);

  // expert residual blocks, routing cols (3,4,6,7,5)
  const int cols[5] = {3, 4, 6, 7, 5};
  for (int i = 0; i < 5; ++i) {
    conv_exp_k<0><<<256, 256, 0, stream>>>(actH, wT1, exp_b1, question, cols[i],
                                           nullptr, actT);
    conv_exp_k<1><<<256, 256, 0, stream>>>(actT, wT2, exp_b2, question, cols[i],
                                           actH, actH);
  }

  // head
  proj_mfma_k<<<512, 256, 0, stream>>>(actH, pwT, proj_b, fbf);
  fc1_mfma_k<<<dim3(16, 32), 256, 0, stream>>>(fbf, fc1_w, part);
  fc1_red_k<<<512, 256, 0, stream>>>(part, fc1_b, f1o);
  fc2_k<<<128, 256, 0, stream>>>(f1o, fc2_w, fc2_b, out);
}